// Round 3
// baseline (1122.410 us; speedup 1.0000x reference)
//
#include <hip/hip_runtime.h>
#include <cfloat>

// ---- problem dims ----
#define NN    16380
#define RR    819
#define APR   20
#define KNB   16
#define HID   64
#define HEADS 8
#define LAYERS 6
#define BINS  100
#define FFN   128
#define N64   (NN*HID)          // 1,048,320

// ---- workspace float offsets ----
#define OFF_S    0
#define OFF_V    (N64)              // 3 planes
#define OFF_Q    (4*N64)
#define OFF_K    (5*N64)
#define OFF_VF   (6*N64)
#define OFF_VV   (7*N64)            // 3 planes
#define OFF_MSG  (10*N64)
#define OFF_U    (11*N64)           // N*128
#define OFF_DIRN (13*N64)           // N*48
#define OFF_C4   (OFF_DIRN + NN*48) // N*4 (float4 coords)
#define OFF_RES  (OFF_C4 + NN*4)    // R*64
#define OFF_NBR  (OFF_RES + RR*64)  // int N*16
#define OFF_BINS (OFF_NBR + NN*16)  // int N*16

__device__ __forceinline__ float gelu_f(float x) {
    float x3 = x*x*x;
    float t = tanhf(0.7978845608028654f*(x + 0.044715f*x3));
    return 0.5f*x*(1.0f+t);
}
__device__ __forceinline__ float sigmoid_f(float x) {
    return 1.0f/(1.0f + expf(-x));
}

// ---------------- pad coords to float4 ----------------
__global__ void pad4_kernel(const float* __restrict__ coords, float4* __restrict__ c4, int n) {
    int i = blockIdx.x*256 + threadIdx.x;
    if (i < n) c4[i] = make_float4(coords[3*i], coords[3*i+1], coords[3*i+2], 0.f);
}

// ---------------- build concat embedding ----------------
__global__ void feat_kernel(const int* __restrict__ aid, const int* __restrict__ rid,
                            const int* __restrict__ eid, const float* __restrict__ ea,
                            const float* __restrict__ er, const float* __restrict__ ee,
                            float* __restrict__ feat, int n) {
    int i = blockIdx.x*256 + threadIdx.x;
    if (i >= n*HID) return;
    int a = i >> 6, e = i & 63;
    float v;
    if (e < 32)      v = ea[aid[a]*32 + e];
    else if (e < 48) v = er[rid[a]*16 + (e-32)];
    else             v = ee[eid[a]*16 + (e-48)];
    feat[i] = v;
}

// ---------------- kNN replicating the reference's fp32 arithmetic ----------------
// Ranking key (matches np):  d2 = fl(fl(sq_i+sq_j) - fl(2*dot)),
//   sq = fl(fl(x^2+y^2)+z^2) (no fma),  dot = fma-chain (BLAS sgemm K=3).
// Fast exact-diff fp32 scan is only a PREFILTER (margin 0.05 covers the
// ~2e-3 cancellation-vs-exact key gap). Stable insert (src-increasing,
// strict <) matches top_k tie-breaking (lower index first).
__global__ __launch_bounds__(1024) void knn_kernel(const float4* __restrict__ c4,
                                                   int* __restrict__ nbr, int* __restrict__ binsO,
                                                   float* __restrict__ dirn, int n) {
    __shared__ float4 tile[1024];
    int tid = threadIdx.x;
    int wave = tid >> 6, lane = tid & 63;
    int dst = blockIdx.x*16 + wave;
    bool wvalid = dst < n;
    int d = wvalid ? dst : 0;
    float4 cd = c4[d];
    float sqd = __fadd_rn(__fadd_rn(__fmul_rn(cd.x,cd.x), __fmul_rn(cd.y,cd.y)),
                          __fmul_rn(cd.z,cd.z));
    float dlist = FLT_MAX;  int ilist = -1;
    float vmax  = FLT_MAX;
    float vmaxf = FLT_MAX;      // prefilter threshold = vmax + margin
    int ntiles = (n + 1023) >> 10;
    for (int t = 0; t < ntiles; ++t) {
        __syncthreads();
        int sidx = (t<<10) + tid;
        tile[tid] = (sidx < n) ? c4[sidx] : make_float4(1e30f,1e30f,1e30f,0.f);
        __syncthreads();
        #pragma unroll 4
        for (int it = 0; it < 16; ++it) {
            int src = (t<<10) + (it<<6) + lane;
            float4 cs = tile[(it<<6) + lane];
            float fdx = cd.x-cs.x, fdy = cd.y-cs.y, fdz = cd.z-cs.z;
            float d2f = fdx*fdx + fdy*fdy + fdz*fdz;     // prefilter only
            if (src == d) d2f = FLT_MAX;
            unsigned long long mask = __ballot(d2f < vmaxf);
            while (mask) {
                int lb = (int)__builtin_ctzll(mask);
                mask &= mask - 1;
                float csx = __shfl(cs.x, lb), csy = __shfl(cs.y, lb), csz = __shfl(cs.z, lb);
                int   ic  = __shfl(src, lb);
                // --- reference-replicated fp32 ranking key ---
                float sqj = __fadd_rn(__fadd_rn(__fmul_rn(csx,csx), __fmul_rn(csy,csy)),
                                      __fmul_rn(csz,csz));
                float dt  = __fmul_rn(cd.x, csx);
                dt = __fmaf_rn(cd.y, csy, dt);
                dt = __fmaf_rn(cd.z, csz, dt);
                float dc = __fsub_rn(__fadd_rn(sqd, sqj), __fmul_rn(2.0f, dt));
                if (dc < vmax) {               // uniform branch
                    float dp = __shfl_up(dlist, 1);
                    int   ip = __shfl_up(ilist, 1);
                    bool below = dc < dlist;
                    bool take  = below && (lane == 0 || dc >= dp);
                    if (lane < 16) {
                        dlist = below ? (take ? dc : dp) : dlist;
                        ilist = below ? (take ? ic : ip) : ilist;
                    }
                    vmax  = __shfl(dlist, 15);
                    vmaxf = vmax + 0.05f;
                }
            }
        }
    }
    if (wvalid && lane < 16) {
        int src = ilist;
        float4 cs = c4[src];
        // --- reference-replicated fp32 edge values ---
        float dx = __fsub_rn(cd.x, cs.x);
        float dy = __fsub_rn(cd.y, cs.y);
        float dz = __fsub_rn(cd.z, cs.z);
        float ss = __fadd_rn(__fadd_rn(__fmul_rn(dx,dx), __fmul_rn(dy,dy)),
                             __fmul_rn(dz,dz));
        float dd = __fsqrt_rn(__fadd_rn(ss, 1e-12f));
        nbr[dst*KNB + lane] = src;
        float bf = __fmul_rn(__fdiv_rn(dd, 10.0f), 100.0f);
        int b = (int)bf;                    // trunc toward zero (d>=0)
        b = min(max(b, 0), BINS-1);
        binsO[dst*KNB + lane] = b;
        dirn[dst*48 + lane*3 + 0] = __fdiv_rn(dx, dd);
        dirn[dst*48 + lane*3 + 1] = __fdiv_rn(dy, dd);
        dirn[dst*48 + lane*3 + 2] = __fdiv_rn(dz, dd);
    }
}

// ---------------- generic fp32 GEMM core: OUT(+res) = act(LN?(A) @ W), optional v-gating ----------------
template<int KDIM, int HO>
__device__ __forceinline__ void gemm_core(const float* __restrict__ A, const float* __restrict__ W,
                                          float* __restrict__ OUT, float* __restrict__ gatev,
                                          int n, int ln, int act, int res) {
    constexpr int TPA = HO/4;        // threads per atom
    constexpr int APB = 256/TPA;     // atoms per block
    __shared__ __align__(16) float sW[KDIM*HO];
    __shared__ float sA[APB][KDIM+1];
    int tid = threadIdx.x;
    int a0 = blockIdx.x * APB;
    for (int i = tid; i < KDIM*HO; i += 256) sW[i] = W[i];
    for (int i = tid; i < APB*KDIM; i += 256) {
        int ar = i / KDIM, ac = i - ar*KDIM;
        int ga = a0 + ar;
        sA[ar][ac] = (ga < n) ? A[ga*KDIM + ac] : 0.f;
    }
    __syncthreads();
    int ar = tid / TPA;
    int cg = tid - ar*TPA;
    int ga = a0 + ar;
    if (ln) {
        constexpr int EPT = KDIM / TPA;
        float vals[EPT]; float s1 = 0.f;
        #pragma unroll
        for (int e = 0; e < EPT; ++e) { vals[e] = sA[ar][cg*EPT + e]; s1 += vals[e]; }
        #pragma unroll
        for (int off = 1; off < TPA; off <<= 1) s1 += __shfl_xor(s1, off);
        float mean = s1 * (1.0f/KDIM);
        float s2 = 0.f;
        #pragma unroll
        for (int e = 0; e < EPT; ++e) { float t = vals[e]-mean; s2 += t*t; }
        #pragma unroll
        for (int off = 1; off < TPA; off <<= 1) s2 += __shfl_xor(s2, off);
        float sc = 1.0f/sqrtf(s2 * (1.0f/KDIM) + 1e-5f);
        #pragma unroll
        for (int e = 0; e < EPT; ++e) sA[ar][cg*EPT + e] = (vals[e]-mean)*sc;
        __syncthreads();
    }
    float4 acc = make_float4(0.f,0.f,0.f,0.f);
    if (res && ga < n) acc = *(const float4*)&OUT[ga*HO + cg*4];
    #pragma unroll 8
    for (int k = 0; k < KDIM; ++k) {
        float av = sA[ar][k];
        float4 w = *(const float4*)&sW[k*HO + cg*4];
        acc.x = fmaf(av, w.x, acc.x);
        acc.y = fmaf(av, w.y, acc.y);
        acc.z = fmaf(av, w.z, acc.z);
        acc.w = fmaf(av, w.w, acc.w);
    }
    if (ga < n) {
        if (act == 1)      { acc.x=gelu_f(acc.x); acc.y=gelu_f(acc.y); acc.z=gelu_f(acc.z); acc.w=gelu_f(acc.w); }
        else if (act == 2) { acc.x=sigmoid_f(acc.x); acc.y=sigmoid_f(acc.y); acc.z=sigmoid_f(acc.z); acc.w=sigmoid_f(acc.w); }
        if (gatev) {
            #pragma unroll
            for (int c = 0; c < 3; ++c) {
                float4* vp = (float4*)&gatev[c*N64 + ga*HID + cg*4];
                float4 vv = *vp;
                vv.x *= acc.x; vv.y *= acc.y; vv.z *= acc.z; vv.w *= acc.w;
                *vp = vv;
            }
        } else {
            *(float4*)&OUT[ga*HO + cg*4] = acc;
        }
    }
}

__global__ void k_gemm64(const float* __restrict__ A, const float* __restrict__ W,
                         float* __restrict__ OUT, int n, int ln, int act, int res) {
    gemm_core<64,64>(A, W, OUT, nullptr, n, ln, act, res);
}
__global__ void k_gate(const float* __restrict__ A, const float* __restrict__ W,
                       float* __restrict__ vbase, int n) {
    gemm_core<64,64>(A, W, nullptr, vbase, n, 1, 2, 0);
}
__global__ void k_ffn1(const float* __restrict__ A, const float* __restrict__ W,
                       float* __restrict__ OUT, int n) {
    gemm_core<64,128>(A, W, OUT, nullptr, n, 1, 1, 0);
}
__global__ void k_ffn2(const float* __restrict__ A, const float* __restrict__ W,
                       float* __restrict__ OUT, int n) {
    gemm_core<128,64>(A, W, OUT, nullptr, n, 0, 0, 1);
}

// jobs 0..2: q/k/v = LN(s)@W;  jobs 3..5: vvals plane = v_plane@Wvec
__global__ void qkvv_kernel(const float* __restrict__ s, const float* __restrict__ v,
                            const float* __restrict__ Wq, const float* __restrict__ Wk,
                            const float* __restrict__ Wv, const float* __restrict__ Wvec,
                            float* __restrict__ q, float* __restrict__ kf,
                            float* __restrict__ vf, float* __restrict__ vv, int n) {
    int job = blockIdx.y;
    const float* A; const float* W; float* O; int ln;
    if (job == 0)      { A = s; W = Wq; O = q;  ln = 1; }
    else if (job == 1) { A = s; W = Wk; O = kf; ln = 1; }
    else if (job == 2) { A = s; W = Wv; O = vf; ln = 1; }
    else { int p = job-3; A = v + p*N64; W = Wvec; O = vv + p*N64; ln = 0; }
    gemm_core<64,64>(A, W, O, nullptr, n, ln, 0, 0);
}

// ---------------- attention: wave per atom, lane = channel ----------------
__global__ void attn_kernel(const float* __restrict__ q, const float* __restrict__ kf,
                            const float* __restrict__ vf, const float* __restrict__ vv,
                            const float* __restrict__ dirn, const int* __restrict__ nbr,
                            const int* __restrict__ bins, const float* __restrict__ db_l,
                            const float* __restrict__ wdir_l,
                            float* __restrict__ msg, float* __restrict__ v, int n) {
    int wave = threadIdx.x >> 6, lane = threadIdx.x & 63;
    int a = blockIdx.x*4 + wave;
    if (a >= n) return;
    int h = lane, hh = h >> 3;
    const float rs = 0.35355339059327373f;   // 1/sqrt(8)
    float qh = q[a*HID + h];
    float lg[KNB]; int nb[KNB];
    #pragma unroll
    for (int k = 0; k < KNB; ++k) {
        int j = nbr[a*KNB + k];
        nb[k] = j;
        float t = qh * kf[j*HID + h];
        t += __shfl_xor(t, 1); t += __shfl_xor(t, 2); t += __shfl_xor(t, 4);
        float bias = db_l[bins[a*KNB+k]*HEADS + hh];
        lg[k] = t*rs + bias;
    }
    float m = lg[0];
    #pragma unroll
    for (int k = 1; k < KNB; ++k) m = fmaxf(m, lg[k]);
    float ssum = 0.f;
    #pragma unroll
    for (int k = 0; k < KNB; ++k) { lg[k] = expf(lg[k]-m); ssum += lg[k]; }
    float inv = 1.0f/ssum;
    float mh = 0.f, a0 = 0.f, a1 = 0.f, a2 = 0.f, s0 = 0.f, s1 = 0.f, s2 = 0.f;
    #pragma unroll
    for (int k = 0; k < KNB; ++k) {
        float w = lg[k]*inv;
        int j = nb[k];
        mh += w * vf[j*HID + h];
        a0 += w * vv[j*HID + h];
        a1 += w * vv[N64   + j*HID + h];
        a2 += w * vv[2*N64 + j*HID + h];
        s0 += w * dirn[a*48 + k*3 + 0];
        s1 += w * dirn[a*48 + k*3 + 1];
        s2 += w * dirn[a*48 + k*3 + 2];
    }
    float wd = wdir_l[h];
    msg[a*HID + h] = mh;
    v[a*HID + h]         += a0 + wd*s0;
    v[N64 + a*HID + h]   += a1 + wd*s1;
    v[2*N64 + a*HID + h] += a2 + wd*s2;
}

// ---------------- residue pooling + head ----------------
__global__ void pool_kernel(const float* __restrict__ s, const int* __restrict__ ridx,
                            float* __restrict__ res, int n) {
    int i = blockIdx.x*256 + threadIdx.x;
    if (i >= n*HID) return;
    int a = i >> 6, c = i & 63;
    atomicAdd(&res[ridx[a]*HID + c], s[i]);
}

__global__ void head_kernel(const float* __restrict__ res, const float* __restrict__ Wout,
                            const float* __restrict__ bout, float* __restrict__ out, int r_total) {
    int wave = threadIdx.x >> 6, lane = threadIdx.x & 63;
    int r = blockIdx.x*4 + wave;
    if (r >= r_total) return;
    float p = res[r*HID + lane] * (1.0f/APR);
    float o0 = p * Wout[lane*2 + 0];
    float o1 = p * Wout[lane*2 + 1];
    #pragma unroll
    for (int off = 1; off < 64; off <<= 1) { o0 += __shfl_xor(o0, off); o1 += __shfl_xor(o1, off); }
    if (lane == 0) { out[r*2+0] = o0 + bout[0]; out[r*2+1] = o1 + bout[1]; }
}

// ---------------- launcher ----------------
extern "C" void kernel_launch(void* const* d_in, const int* in_sizes, int n_in,
                              void* d_out, int out_size, void* d_ws, size_t ws_size,
                              hipStream_t stream) {
    const float* coords    = (const float*)d_in[0];
    const int*   atom_ids  = (const int*)d_in[1];
    const int*   res_ids   = (const int*)d_in[2];
    const int*   elem_ids  = (const int*)d_in[3];
    const int*   ridx      = (const int*)d_in[4];
    const float* emb_atom  = (const float*)d_in[5];
    const float* emb_res   = (const float*)d_in[6];
    const float* emb_elem  = (const float*)d_in[7];
    const float* Win       = (const float*)d_in[8];
    const float* Wq        = (const float*)d_in[9];
    const float* Wk        = (const float*)d_in[10];
    const float* Wv        = (const float*)d_in[11];
    const float* Wvec      = (const float*)d_in[12];
    const float* wdir      = (const float*)d_in[13];
    const float* dist_bias = (const float*)d_in[14];
    const float* Wo        = (const float*)d_in[15];
    const float* W1        = (const float*)d_in[16];
    const float* W2        = (const float*)d_in[17];
    const float* Wg        = (const float*)d_in[18];
    const float* Wout      = (const float*)d_in[19];
    const float* bout      = (const float*)d_in[20];
    float* out = (float*)d_out;

    float* ws = (float*)d_ws;
    float* s    = ws + OFF_S;
    float* v    = ws + OFF_V;
    float* q    = ws + OFF_Q;
    float* kf   = ws + OFF_K;
    float* vf   = ws + OFF_VF;
    float* vv   = ws + OFF_VV;
    float* msg  = ws + OFF_MSG;
    float* u    = ws + OFF_U;
    float* dirn = ws + OFF_DIRN;
    float4* c4  = (float4*)(ws + OFF_C4);
    float* resb = ws + OFF_RES;
    int* nbr    = (int*)(ws + OFF_NBR);
    int* binsb  = (int*)(ws + OFF_BINS);

    hipMemsetAsync(v,    0, (size_t)3*N64*sizeof(float), stream);
    hipMemsetAsync(resb, 0, (size_t)RR*HID*sizeof(float), stream);

    pad4_kernel<<<(NN+255)/256, 256, 0, stream>>>(coords, c4, NN);
    feat_kernel<<<(NN*HID+255)/256, 256, 0, stream>>>(atom_ids, res_ids, elem_ids,
                                                      emb_atom, emb_res, emb_elem, msg, NN);
    k_gemm64<<<(NN+15)/16, 256, 0, stream>>>(msg, Win, s, NN, 0, 0, 0);
    knn_kernel<<<(NN+15)/16, 1024, 0, stream>>>(c4, nbr, binsb, dirn, NN);

    for (int l = 0; l < LAYERS; ++l) {
        qkvv_kernel<<<dim3((NN+15)/16, 6), 256, 0, stream>>>(
            s, v, Wq + l*HID*HID, Wk + l*HID*HID, Wv + l*HID*HID, Wvec + l*HID*HID,
            q, kf, vf, vv, NN);
        attn_kernel<<<(NN+3)/4, 256, 0, stream>>>(
            q, kf, vf, vv, dirn, nbr, binsb,
            dist_bias + l*BINS*HEADS, wdir + l*HID, msg, v, NN);
        k_gemm64<<<(NN+15)/16, 256, 0, stream>>>(msg, Wo + l*HID*HID, s, NN, 0, 0, 1);
        k_ffn1<<<(NN+7)/8, 256, 0, stream>>>(s, W1 + l*HID*FFN, u, NN);
        k_gate<<<(NN+15)/16, 256, 0, stream>>>(s, Wg + l*HID*HID, v, NN);
        k_ffn2<<<(NN+15)/16, 256, 0, stream>>>(u, W2 + l*FFN*HID, s, NN);
    }

    pool_kernel<<<(NN*HID+255)/256, 256, 0, stream>>>(s, ridx, resb, NN);
    head_kernel<<<(RR+3)/4, 256, 0, stream>>>(resb, Wout, bout, out, RR);
}